// Round 1
// baseline (394.213 us; speedup 1.0000x reference)
//
#include <hip/hip_runtime.h>

#define S_LEN 2048
#define BATCH 2
#define DM    1024
#define NH    16
#define NKV   4
#define HD    64
#define MROWS (BATCH * S_LEN)   // 4096
#define NQKV  1536              // 1024 q + 512 kv

typedef __attribute__((ext_vector_type(8))) short bf16x8;
typedef __attribute__((ext_vector_type(4))) float f32x4;

__device__ __forceinline__ unsigned short f2bf(float f) {
  unsigned int u = __float_as_uint(f);
  u += 0x7FFF + ((u >> 16) & 1);   // RNE
  return (unsigned short)(u >> 16);
}

// ---------------- x -> bf16 ----------------
__global__ __launch_bounds__(256) void cvt_x_kernel(const float* __restrict__ x,
                                                    unsigned short* __restrict__ xb, int n) {
  int i = (blockIdx.x * 256 + threadIdx.x) * 4;
  if (i < n) {
    float4 v = *reinterpret_cast<const float4*>(x + i);
    xb[i + 0] = f2bf(v.x);
    xb[i + 1] = f2bf(v.y);
    xb[i + 2] = f2bf(v.z);
    xb[i + 3] = f2bf(v.w);
  }
}

// ---------------- W (RxC fp32) -> W^T (CxR bf16) ----------------
__global__ __launch_bounds__(256) void transpose_cvt_kernel(const float* __restrict__ in,
                                                            unsigned short* __restrict__ out,
                                                            int R, int C) {
  __shared__ float tile[64][65];
  int r0 = blockIdx.y * 64, c0 = blockIdx.x * 64;
  int t = threadIdx.x;
  int rl = t >> 2, cs = (t & 3) * 16;
#pragma unroll
  for (int k = 0; k < 4; ++k) {
    float4 v = *reinterpret_cast<const float4*>(in + (size_t)(r0 + rl) * C + c0 + cs + 4 * k);
    tile[rl][cs + 4 * k + 0] = v.x;
    tile[rl][cs + 4 * k + 1] = v.y;
    tile[rl][cs + 4 * k + 2] = v.z;
    tile[rl][cs + 4 * k + 3] = v.w;
  }
  __syncthreads();
  int cl = t >> 2, rs = (t & 3) * 16;
  bf16x8 v0, v1;
#pragma unroll
  for (int i = 0; i < 8; ++i) v0[i] = (short)f2bf(tile[rs + i][cl]);
#pragma unroll
  for (int i = 0; i < 8; ++i) v1[i] = (short)f2bf(tile[rs + 8 + i][cl]);
  unsigned short* dst = out + (size_t)(c0 + cl) * R + r0 + rs;
  *reinterpret_cast<bf16x8*>(dst) = v0;
  *reinterpret_cast<bf16x8*>(dst + 8) = v1;
}

// ---------------- bf16 GEMM: C(MxN fp32) = A(MxK) @ BT(NxK)^T ----------------
__global__ __launch_bounds__(256) void gemm_bt_kernel(const unsigned short* __restrict__ A,
                                                      const unsigned short* __restrict__ BT,
                                                      float* __restrict__ C,
                                                      int M, int N, int K) {
  __shared__ __align__(16) unsigned short As[64][72];
  __shared__ __align__(16) unsigned short Bs[64][72];
  int row0 = blockIdx.y * 64, col0 = blockIdx.x * 64;
  int t = threadIdx.x;
  int w = t >> 6, lane = t & 63, quad = lane >> 4, l16 = lane & 15;
  int sr = t >> 2, scc = (t & 3) * 16;

  f32x4 acc[4];
#pragma unroll
  for (int i = 0; i < 4; ++i) acc[i] = (f32x4){0.f, 0.f, 0.f, 0.f};

  for (int k0 = 0; k0 < K; k0 += 64) {
    const bf16x8* ga = reinterpret_cast<const bf16x8*>(A + (size_t)(row0 + sr) * K + k0 + scc);
    const bf16x8* gb = reinterpret_cast<const bf16x8*>(BT + (size_t)(col0 + sr) * K + k0 + scc);
    bf16x8 a0 = ga[0], a1 = ga[1];
    bf16x8 b0 = gb[0], b1 = gb[1];
    *reinterpret_cast<bf16x8*>(&As[sr][scc]) = a0;
    *reinterpret_cast<bf16x8*>(&As[sr][scc + 8]) = a1;
    *reinterpret_cast<bf16x8*>(&Bs[sr][scc]) = b0;
    *reinterpret_cast<bf16x8*>(&Bs[sr][scc + 8]) = b1;
    __syncthreads();
#pragma unroll
    for (int ks = 0; ks < 2; ++ks) {
      bf16x8 af = *reinterpret_cast<const bf16x8*>(&As[w * 16 + l16][ks * 32 + quad * 8]);
#pragma unroll
      for (int cb = 0; cb < 4; ++cb) {
        bf16x8 bf = *reinterpret_cast<const bf16x8*>(&Bs[cb * 16 + l16][ks * 32 + quad * 8]);
        acc[cb] = __builtin_amdgcn_mfma_f32_16x16x32_bf16(af, bf, acc[cb], 0, 0, 0);
      }
    }
    __syncthreads();
  }
#pragma unroll
  for (int cb = 0; cb < 4; ++cb)
#pragma unroll
    for (int rg = 0; rg < 4; ++rg) {
      int row = row0 + w * 16 + quad * 4 + rg;
      C[(size_t)row * N + col0 + cb * 16 + l16] = acc[cb][rg];
    }
}

// ---------------- RMSNorm + RoPE for q and k ----------------
// qkv: (4096 x 1536) fp32 [cols 0..1023 q, 1024..1279 k, 1280..1535 v]
// qb: (B, NH, S, 64) bf16 ; kbuf: (B, NKV, S, 64) bf16
__global__ __launch_bounds__(256) void norm_rope_kernel(const float* __restrict__ qkv,
                                                        const float* __restrict__ q_scale,
                                                        const float* __restrict__ k_scale,
                                                        unsigned short* __restrict__ qb,
                                                        unsigned short* __restrict__ kbuf) {
  int wid = (blockIdx.x * 256 + threadIdx.x) >> 6;
  int lane = threadIdx.x & 63;
  int r = wid / 20, hh = wid % 20;         // r = b*S + s
  int b = r >> 11, s = r & 2047;
  const float* src;
  const float* scale;
  unsigned short* dst;
  if (hh < 16) {
    src = qkv + (size_t)r * NQKV + hh * 64;
    scale = q_scale;
    dst = qb + ((size_t)(b * NH + hh) * S_LEN + s) * HD;
  } else {
    int kvh = hh - 16;
    src = qkv + (size_t)r * NQKV + 1024 + kvh * 64;
    scale = k_scale;
    dst = kbuf + ((size_t)(b * NKV + kvh) * S_LEN + s) * HD;
  }
  float v = src[lane];
  float ss = v * v;
#pragma unroll
  for (int m = 1; m < 64; m <<= 1) ss += __shfl_xor(ss, m, 64);
  float rms = sqrtf(ss * (1.0f / 64.0f) + 1e-5f);
  float nv = v / rms * scale[lane];
  int dh = lane & 31;
  float inv = powf(10000.0f, -(float)dh * (1.0f / 32.0f));
  float f = (float)s * inv;
  float c = cosf(f), sn = sinf(f);
  float partner = __shfl_xor(nv, 32, 64);
  float outv = (lane < 32) ? (nv * c - partner * sn) : (partner * sn + nv * c);
  dst[lane] = f2bf(outv);
}

// ---------------- V: (s,d) fp32 slice of qkv -> vT (B,NKV,64,S) bf16 ----------------
__global__ __launch_bounds__(256) void v_transpose_kernel(const float* __restrict__ qkv,
                                                          unsigned short* __restrict__ vt) {
  __shared__ float tile[64][65];
  int bkv = blockIdx.x >> 5;              // 0..7 = b*NKV+kvh
  int b = bkv >> 2, kvh = bkv & 3;
  int s0 = (blockIdx.x & 31) * 64;
  int t = threadIdx.x;
  int sl = t >> 2, ds = (t & 3) * 16;
  const float* src = qkv + (size_t)(b * S_LEN + s0 + sl) * NQKV + 1280 + kvh * 64 + ds;
#pragma unroll
  for (int k = 0; k < 4; ++k) {
    float4 v = *reinterpret_cast<const float4*>(src + 4 * k);
    tile[sl][ds + 4 * k + 0] = v.x;
    tile[sl][ds + 4 * k + 1] = v.y;
    tile[sl][ds + 4 * k + 2] = v.z;
    tile[sl][ds + 4 * k + 3] = v.w;
  }
  __syncthreads();
  int d = t >> 2, ssg = (t & 3) * 16;
  bf16x8 v0, v1;
#pragma unroll
  for (int i = 0; i < 8; ++i) v0[i] = (short)f2bf(tile[ssg + i][d]);
#pragma unroll
  for (int i = 0; i < 8; ++i) v1[i] = (short)f2bf(tile[ssg + 8 + i][d]);
  unsigned short* dst = vt + ((size_t)bkv * 64 + d) * S_LEN + s0 + ssg;
  *reinterpret_cast<bf16x8*>(dst) = v0;
  *reinterpret_cast<bf16x8*>(dst + 8) = v1;
}

// ---------------- causal flash attention ----------------
// qb (B,NH,S,64), kbuf (B,NKV,S,64), vt (B,NKV,64,S) -> ctx (B*S, 1024) bf16
__global__ __launch_bounds__(256) void attn_kernel(const unsigned short* __restrict__ qb,
                                                   const unsigned short* __restrict__ kbuf,
                                                   const unsigned short* __restrict__ vt,
                                                   unsigned short* __restrict__ ctx) {
  __shared__ __align__(16) unsigned short Plds[4][16][40];
  int qt = blockIdx.x & 31;
  int bh = blockIdx.x >> 5;
  int b = bh >> 4, h = bh & 15, kvh = h >> 2;
  int w = threadIdx.x >> 6, lane = threadIdx.x & 63;
  int quad = lane >> 4, l16 = lane & 15;
  int q0 = qt * 64 + w * 16;
  const unsigned short* Q = qb + (size_t)(b * NH + h) * S_LEN * HD;
  const unsigned short* Kh = kbuf + (size_t)(b * NKV + kvh) * S_LEN * HD;
  const unsigned short* Vh = vt + (size_t)(b * NKV + kvh) * HD * S_LEN;

  bf16x8 aq0 = *reinterpret_cast<const bf16x8*>(Q + (q0 + l16) * HD + quad * 8);
  bf16x8 aq1 = *reinterpret_cast<const bf16x8*>(Q + (q0 + l16) * HD + 32 + quad * 8);

  f32x4 o0 = {0.f, 0.f, 0.f, 0.f}, o1 = o0, o2 = o0, o3 = o0;
  float m_i[4], l_i[4];
#pragma unroll
  for (int i = 0; i < 4; ++i) { m_i[i] = -1e30f; l_i[i] = 0.f; }

  // block-uniform trip count (max over the 4 waves) so __syncthreads is legal
  int nkb = (qt * 64 + 95) >> 5;
  for (int kbi = 0; kbi < nkb; ++kbi) {
    int kbase = kbi << 5;
    const unsigned short* Kp = Kh + (size_t)kbase * HD;
    bf16x8 bk00 = *reinterpret_cast<const bf16x8*>(Kp + l16 * HD + quad * 8);
    bf16x8 bk01 = *reinterpret_cast<const bf16x8*>(Kp + l16 * HD + 32 + quad * 8);
    bf16x8 bk10 = *reinterpret_cast<const bf16x8*>(Kp + (16 + l16) * HD + quad * 8);
    bf16x8 bk11 = *reinterpret_cast<const bf16x8*>(Kp + (16 + l16) * HD + 32 + quad * 8);
    f32x4 s0 = {0.f, 0.f, 0.f, 0.f}, s1 = {0.f, 0.f, 0.f, 0.f};
    s0 = __builtin_amdgcn_mfma_f32_16x16x32_bf16(aq0, bk00, s0, 0, 0, 0);
    s0 = __builtin_amdgcn_mfma_f32_16x16x32_bf16(aq1, bk01, s0, 0, 0, 0);
    s1 = __builtin_amdgcn_mfma_f32_16x16x32_bf16(aq0, bk10, s1, 0, 0, 0);
    s1 = __builtin_amdgcn_mfma_f32_16x16x32_bf16(aq1, bk11, s1, 0, 0, 0);

#pragma unroll
    for (int rg = 0; rg < 4; ++rg) {
      int qr = q0 + quad * 4 + rg;
      float v0 = s0[rg] * 0.125f;
      if (kbase + l16 > qr) v0 = -1e30f;
      float v1 = s1[rg] * 0.125f;
      if (kbase + 16 + l16 > qr) v1 = -1e30f;
      float mx = fmaxf(v0, v1);
      mx = fmaxf(mx, __shfl_xor(mx, 1, 64));
      mx = fmaxf(mx, __shfl_xor(mx, 2, 64));
      mx = fmaxf(mx, __shfl_xor(mx, 4, 64));
      mx = fmaxf(mx, __shfl_xor(mx, 8, 64));
      float mnew = fmaxf(m_i[rg], mx);
      float alpha = __expf(m_i[rg] - mnew);
      m_i[rg] = mnew;
      float p0 = __expf(v0 - mnew);
      float p1 = __expf(v1 - mnew);
      float rs = p0 + p1;
      rs += __shfl_xor(rs, 1, 64);
      rs += __shfl_xor(rs, 2, 64);
      rs += __shfl_xor(rs, 4, 64);
      rs += __shfl_xor(rs, 8, 64);
      l_i[rg] = l_i[rg] * alpha + rs;
      o0[rg] *= alpha; o1[rg] *= alpha; o2[rg] *= alpha; o3[rg] *= alpha;
      Plds[w][quad * 4 + rg][l16] = f2bf(p0);
      Plds[w][quad * 4 + rg][16 + l16] = f2bf(p1);
    }
    __syncthreads();   // P tile visible (also orders across waves; uniform trip count)
    bf16x8 pa = *reinterpret_cast<const bf16x8*>(&Plds[w][l16][quad * 8]);
    const unsigned short* Vp = Vh + kbase;
    bf16x8 bv0 = *reinterpret_cast<const bf16x8*>(Vp + (size_t)(0 + l16) * S_LEN + quad * 8);
    bf16x8 bv1 = *reinterpret_cast<const bf16x8*>(Vp + (size_t)(16 + l16) * S_LEN + quad * 8);
    bf16x8 bv2 = *reinterpret_cast<const bf16x8*>(Vp + (size_t)(32 + l16) * S_LEN + quad * 8);
    bf16x8 bv3 = *reinterpret_cast<const bf16x8*>(Vp + (size_t)(48 + l16) * S_LEN + quad * 8);
    o0 = __builtin_amdgcn_mfma_f32_16x16x32_bf16(pa, bv0, o0, 0, 0, 0);
    o1 = __builtin_amdgcn_mfma_f32_16x16x32_bf16(pa, bv1, o1, 0, 0, 0);
    o2 = __builtin_amdgcn_mfma_f32_16x16x32_bf16(pa, bv2, o2, 0, 0, 0);
    o3 = __builtin_amdgcn_mfma_f32_16x16x32_bf16(pa, bv3, o3, 0, 0, 0);
    __syncthreads();   // protect P tile from next iteration's writes
  }

#pragma unroll
  for (int rg = 0; rg < 4; ++rg) {
    int srow = q0 + quad * 4 + rg;
    float inv_l = 1.0f / l_i[rg];
    size_t base = ((size_t)b * S_LEN + srow) * DM + h * HD;
    ctx[base + 0 * 16 + l16] = f2bf(o0[rg] * inv_l);
    ctx[base + 1 * 16 + l16] = f2bf(o1[rg] * inv_l);
    ctx[base + 2 * 16 + l16] = f2bf(o2[rg] * inv_l);
    ctx[base + 3 * 16 + l16] = f2bf(o3[rg] * inv_l);
  }
}

// ---------------- launch ----------------
extern "C" void kernel_launch(void* const* d_in, const int* in_sizes, int n_in,
                              void* d_out, int out_size, void* d_ws, size_t ws_size,
                              hipStream_t stream) {
  const float* x = (const float*)d_in[0];
  const float* Wq = (const float*)d_in[1];
  const float* Wkv = (const float*)d_in[2];
  const float* Wo = (const float*)d_in[3];
  const float* q_scale = (const float*)d_in[4];
  const float* k_scale = (const float*)d_in[5];
  float* out = (float*)d_out;

  char* ws = (char*)d_ws;
  size_t off = 0;
  auto alloc = [&](size_t bytes) {
    void* p = ws + off;
    off += (bytes + 255) & ~(size_t)255;
    return p;
  };
  unsigned short* xb = (unsigned short*)alloc((size_t)MROWS * DM * 2);
  unsigned short* wt1 = (unsigned short*)alloc((size_t)NQKV * DM * 2);   // [Wq^T ; Wkv^T]
  unsigned short* wot = (unsigned short*)alloc((size_t)DM * DM * 2);
  float* qkv = (float*)alloc((size_t)MROWS * NQKV * 4);
  unsigned short* qb = (unsigned short*)alloc((size_t)BATCH * NH * S_LEN * HD * 2);
  unsigned short* kbuf = (unsigned short*)alloc((size_t)BATCH * NKV * S_LEN * HD * 2);
  unsigned short* vt = (unsigned short*)alloc((size_t)BATCH * NKV * HD * S_LEN * 2);
  unsigned short* ctx = (unsigned short*)alloc((size_t)MROWS * DM * 2);

  cvt_x_kernel<<<(MROWS * DM) / 1024, 256, 0, stream>>>(x, xb, MROWS * DM);
  transpose_cvt_kernel<<<dim3(16, 16), 256, 0, stream>>>(Wq, wt1, 1024, 1024);
  transpose_cvt_kernel<<<dim3(8, 16), 256, 0, stream>>>(Wkv, wt1 + 1024 * 1024, 1024, 512);
  transpose_cvt_kernel<<<dim3(16, 16), 256, 0, stream>>>(Wo, wot, 1024, 1024);

  gemm_bt_kernel<<<dim3(NQKV / 64, MROWS / 64), 256, 0, stream>>>(xb, wt1, qkv, MROWS, NQKV, DM);

  norm_rope_kernel<<<(MROWS * 20) / 4, 256, 0, stream>>>(qkv, q_scale, k_scale, qb, kbuf);
  v_transpose_kernel<<<256, 256, 0, stream>>>(qkv, vt);

  attn_kernel<<<BATCH * NH * (S_LEN / 64), 256, 0, stream>>>(qb, kbuf, vt, ctx);

  gemm_bt_kernel<<<dim3(DM / 64, MROWS / 64), 256, 0, stream>>>(ctx, wot, out, MROWS, DM, DM);
}

// Round 2
// 297.759 us; speedup vs baseline: 1.3239x; 1.3239x over previous
//
#include <hip/hip_runtime.h>

#define S_LEN 2048
#define BATCH 2
#define DM    1024
#define NH    16
#define NKV   4
#define HD    64
#define MROWS (BATCH * S_LEN)   // 4096
#define NQKV  1536              // 1024 q + 512 kv

typedef __attribute__((ext_vector_type(8))) short bf16x8;
typedef __attribute__((ext_vector_type(4))) short s16x4;
typedef __attribute__((ext_vector_type(4))) float f32x4;

__device__ __forceinline__ unsigned short f2bf(float f) {
  unsigned int u = __float_as_uint(f);
  u += 0x7FFF + ((u >> 16) & 1);   // RNE
  return (unsigned short)(u >> 16);
}

// ---------------- x -> bf16 ----------------
__global__ __launch_bounds__(256) void cvt_x_kernel(const float* __restrict__ x,
                                                    unsigned short* __restrict__ xb, int n) {
  int i = (blockIdx.x * 256 + threadIdx.x) * 4;
  if (i < n) {
    float4 v = *reinterpret_cast<const float4*>(x + i);
    xb[i + 0] = f2bf(v.x);
    xb[i + 1] = f2bf(v.y);
    xb[i + 2] = f2bf(v.z);
    xb[i + 3] = f2bf(v.w);
  }
}

// ---------------- W (RxC fp32) -> W^T (CxR bf16) ----------------
__global__ __launch_bounds__(256) void transpose_cvt_kernel(const float* __restrict__ in,
                                                            unsigned short* __restrict__ out,
                                                            int R, int C) {
  __shared__ float tile[64][65];
  int r0 = blockIdx.y * 64, c0 = blockIdx.x * 64;
  int t = threadIdx.x;
  int rl = t >> 2, cs = (t & 3) * 16;
#pragma unroll
  for (int k = 0; k < 4; ++k) {
    float4 v = *reinterpret_cast<const float4*>(in + (size_t)(r0 + rl) * C + c0 + cs + 4 * k);
    tile[rl][cs + 4 * k + 0] = v.x;
    tile[rl][cs + 4 * k + 1] = v.y;
    tile[rl][cs + 4 * k + 2] = v.z;
    tile[rl][cs + 4 * k + 3] = v.w;
  }
  __syncthreads();
  int cl = t >> 2, rs = (t & 3) * 16;
  bf16x8 v0, v1;
#pragma unroll
  for (int i = 0; i < 8; ++i) v0[i] = (short)f2bf(tile[rs + i][cl]);
#pragma unroll
  for (int i = 0; i < 8; ++i) v1[i] = (short)f2bf(tile[rs + 8 + i][cl]);
  unsigned short* dst = out + (size_t)(c0 + cl) * R + r0 + rs;
  *reinterpret_cast<bf16x8*>(dst) = v0;
  *reinterpret_cast<bf16x8*>(dst + 8) = v1;
}

// ------- bf16 GEMM (128x128 tile, 4 waves, 4x4 16x16x32 MFMA per wave) -------
// C(MxN fp32) = A(MxK) @ BT(NxK)^T
__global__ __launch_bounds__(256) void gemm_bt_kernel(const unsigned short* __restrict__ A,
                                                      const unsigned short* __restrict__ BT,
                                                      float* __restrict__ C,
                                                      int M, int N, int K) {
  __shared__ __align__(16) unsigned short As[128][72];
  __shared__ __align__(16) unsigned short Bs[128][72];
  int row0 = blockIdx.y * 128, col0 = blockIdx.x * 128;
  int t = threadIdx.x;
  int w = t >> 6, lane = t & 63, quad = lane >> 4, l16 = lane & 15;
  int wm = w & 1, wn = w >> 1;
  int sr = t >> 2, scc = (t & 3) * 16;

  f32x4 acc[4][4];
#pragma unroll
  for (int i = 0; i < 4; ++i)
#pragma unroll
    for (int j = 0; j < 4; ++j) acc[i][j] = (f32x4){0.f, 0.f, 0.f, 0.f};

  for (int k0 = 0; k0 < K; k0 += 64) {
    const bf16x8* ga0 = reinterpret_cast<const bf16x8*>(A + (size_t)(row0 + sr) * K + k0 + scc);
    const bf16x8* ga1 = reinterpret_cast<const bf16x8*>(A + (size_t)(row0 + 64 + sr) * K + k0 + scc);
    const bf16x8* gb0 = reinterpret_cast<const bf16x8*>(BT + (size_t)(col0 + sr) * K + k0 + scc);
    const bf16x8* gb1 = reinterpret_cast<const bf16x8*>(BT + (size_t)(col0 + 64 + sr) * K + k0 + scc);
    bf16x8 a00 = ga0[0], a01 = ga0[1], a10 = ga1[0], a11 = ga1[1];
    bf16x8 b00 = gb0[0], b01 = gb0[1], b10 = gb1[0], b11 = gb1[1];
    *reinterpret_cast<bf16x8*>(&As[sr][scc]) = a00;
    *reinterpret_cast<bf16x8*>(&As[sr][scc + 8]) = a01;
    *reinterpret_cast<bf16x8*>(&As[64 + sr][scc]) = a10;
    *reinterpret_cast<bf16x8*>(&As[64 + sr][scc + 8]) = a11;
    *reinterpret_cast<bf16x8*>(&Bs[sr][scc]) = b00;
    *reinterpret_cast<bf16x8*>(&Bs[sr][scc + 8]) = b01;
    *reinterpret_cast<bf16x8*>(&Bs[64 + sr][scc]) = b10;
    *reinterpret_cast<bf16x8*>(&Bs[64 + sr][scc + 8]) = b11;
    __syncthreads();
#pragma unroll
    for (int ks = 0; ks < 2; ++ks) {
      bf16x8 af[4], bfr[4];
#pragma unroll
      for (int i = 0; i < 4; ++i)
        af[i] = *reinterpret_cast<const bf16x8*>(&As[wm * 64 + i * 16 + l16][ks * 32 + quad * 8]);
#pragma unroll
      for (int i = 0; i < 4; ++i)
        bfr[i] = *reinterpret_cast<const bf16x8*>(&Bs[wn * 64 + i * 16 + l16][ks * 32 + quad * 8]);
#pragma unroll
      for (int am = 0; am < 4; ++am)
#pragma unroll
        for (int bn = 0; bn < 4; ++bn)
          acc[am][bn] = __builtin_amdgcn_mfma_f32_16x16x32_bf16(af[am], bfr[bn], acc[am][bn], 0, 0, 0);
    }
    __syncthreads();
  }
#pragma unroll
  for (int am = 0; am < 4; ++am)
#pragma unroll
    for (int bn = 0; bn < 4; ++bn) {
      int row = row0 + wm * 64 + am * 16 + quad * 4;
      float* Cp = C + (size_t)row * N + col0 + wn * 64 + bn * 16 + l16;
#pragma unroll
      for (int rg = 0; rg < 4; ++rg) Cp[(size_t)rg * N] = acc[am][bn][rg];
    }
}

// ---------------- RMSNorm + RoPE for q and k ----------------
// k additionally pre-scaled by 0.125*log2(e) so attention softmax runs in exp2 domain
__global__ __launch_bounds__(256) void norm_rope_kernel(const float* __restrict__ qkv,
                                                        const float* __restrict__ q_scale,
                                                        const float* __restrict__ k_scale,
                                                        unsigned short* __restrict__ qb,
                                                        unsigned short* __restrict__ kbuf) {
  int wid = (blockIdx.x * 256 + threadIdx.x) >> 6;
  int lane = threadIdx.x & 63;
  int r = wid / 20, hh = wid % 20;         // r = b*S + s
  int b = r >> 11, s = r & 2047;
  const float* src;
  const float* scale;
  unsigned short* dst;
  float post;
  if (hh < 16) {
    src = qkv + (size_t)r * NQKV + hh * 64;
    scale = q_scale;
    dst = qb + ((size_t)(b * NH + hh) * S_LEN + s) * HD;
    post = 1.0f;
  } else {
    int kvh = hh - 16;
    src = qkv + (size_t)r * NQKV + 1024 + kvh * 64;
    scale = k_scale;
    dst = kbuf + ((size_t)(b * NKV + kvh) * S_LEN + s) * HD;
    post = 0.125f * 1.44269504088896f;   // fold score scale + log2(e) into k
  }
  float v = src[lane];
  float ss = v * v;
#pragma unroll
  for (int m = 1; m < 64; m <<= 1) ss += __shfl_xor(ss, m, 64);
  float rms = sqrtf(ss * (1.0f / 64.0f) + 1e-5f);
  float nv = v / rms * scale[lane];
  int dh = lane & 31;
  float inv = exp2f((float)dh * (-13.2877123795495f / 32.0f));  // 10000^(-dh/32)
  float f = (float)s * inv;
  float c = cosf(f), sn = sinf(f);
  float partner = __shfl_xor(nv, 32, 64);
  float outv = (lane < 32) ? (nv * c - partner * sn) : (partner * sn + nv * c);
  dst[lane] = f2bf(outv * post);
}

// ---------------- V: (s,d) fp32 slice of qkv -> vT (B,NKV,64,S) bf16 ----------------
__global__ __launch_bounds__(256) void v_transpose_kernel(const float* __restrict__ qkv,
                                                          unsigned short* __restrict__ vt) {
  __shared__ float tile[64][65];
  int bkv = blockIdx.x >> 5;              // 0..7 = b*NKV+kvh
  int b = bkv >> 2, kvh = bkv & 3;
  int s0 = (blockIdx.x & 31) * 64;
  int t = threadIdx.x;
  int sl = t >> 2, ds = (t & 3) * 16;
  const float* src = qkv + (size_t)(b * S_LEN + s0 + sl) * NQKV + 1280 + kvh * 64 + ds;
#pragma unroll
  for (int k = 0; k < 4; ++k) {
    float4 v = *reinterpret_cast<const float4*>(src + 4 * k);
    tile[sl][ds + 4 * k + 0] = v.x;
    tile[sl][ds + 4 * k + 1] = v.y;
    tile[sl][ds + 4 * k + 2] = v.z;
    tile[sl][ds + 4 * k + 3] = v.w;
  }
  __syncthreads();
  int d = t >> 2, ssg = (t & 3) * 16;
  bf16x8 v0, v1;
#pragma unroll
  for (int i = 0; i < 8; ++i) v0[i] = (short)f2bf(tile[ssg + i][d]);
#pragma unroll
  for (int i = 0; i < 8; ++i) v1[i] = (short)f2bf(tile[ssg + 8 + i][d]);
  unsigned short* dst = vt + ((size_t)bkv * 64 + d) * S_LEN + s0 + ssg;
  *reinterpret_cast<bf16x8*>(dst) = v0;
  *reinterpret_cast<bf16x8*>(dst + 8) = v1;
}

// ---------------- causal flash attention (transposed scores) ----------------
// S^T = K·Q^T  (per-lane softmax state: q = lane&15)
// O^T = V^T·P^T (alpha/1-over-l applied per-lane, no shuffles)
// P^T round-trips wave-private LDS (no barriers needed).
__global__ __launch_bounds__(256) void attn_kernel(const unsigned short* __restrict__ qb,
                                                   const unsigned short* __restrict__ kbuf,
                                                   const unsigned short* __restrict__ vt,
                                                   unsigned short* __restrict__ ctx) {
  __shared__ __align__(16) unsigned short PT[4][16][72];   // [wave][q][key 0..63]
  int qt = 31 - (int)(blockIdx.x >> 5);    // heavy tiles dispatched first
  int bh = blockIdx.x & 31;
  int b = bh >> 4, h = bh & 15, kvh = h >> 2;
  int w = threadIdx.x >> 6, lane = threadIdx.x & 63;
  int quad = lane >> 4, l16 = lane & 15;
  int q0 = qt * 64 + w * 16;
  int qr = q0 + l16;
  const unsigned short* Q = qb + (size_t)(b * NH + h) * S_LEN * HD;
  const unsigned short* Kh = kbuf + (size_t)(b * NKV + kvh) * S_LEN * HD;
  const unsigned short* Vh = vt + (size_t)(b * NKV + kvh) * HD * S_LEN;

  // Q as B-operand fragments (loop-invariant)
  bf16x8 bq0 = *reinterpret_cast<const bf16x8*>(Q + (size_t)(q0 + l16) * HD + quad * 8);
  bf16x8 bq1 = *reinterpret_cast<const bf16x8*>(Q + (size_t)(q0 + l16) * HD + 32 + quad * 8);

  f32x4 ot[4];
#pragma unroll
  for (int i = 0; i < 4; ++i) ot[i] = (f32x4){0.f, 0.f, 0.f, 0.f};
  float m_i = -1e30f, l_i = 0.f;

  int nkb = qt + 1;
  for (int kbi = 0; kbi < nkb; ++kbi) {
    int kbase = kbi << 6;
    f32x4 sc[4];
#pragma unroll
    for (int km = 0; km < 4; ++km) {
      const unsigned short* Kp = Kh + (size_t)(kbase + km * 16 + l16) * HD;
      bf16x8 ak0 = *reinterpret_cast<const bf16x8*>(Kp + quad * 8);
      bf16x8 ak1 = *reinterpret_cast<const bf16x8*>(Kp + 32 + quad * 8);
      f32x4 s = {0.f, 0.f, 0.f, 0.f};
      s = __builtin_amdgcn_mfma_f32_16x16x32_bf16(ak0, bq0, s, 0, 0, 0);
      s = __builtin_amdgcn_mfma_f32_16x16x32_bf16(ak1, bq1, s, 0, 0, 0);
      sc[km] = s;
    }
    float mx = -1e30f;
#pragma unroll
    for (int km = 0; km < 4; ++km)
#pragma unroll
      for (int rg = 0; rg < 4; ++rg) {
        float v = sc[km][rg];
        if (kbase + km * 16 + quad * 4 + rg > qr) v = -1e30f;
        sc[km][rg] = v;
        mx = fmaxf(mx, v);
      }
    mx = fmaxf(mx, __shfl_xor(mx, 16, 64));
    mx = fmaxf(mx, __shfl_xor(mx, 32, 64));
    float mnew = fmaxf(m_i, mx);
    float alpha = exp2f(m_i - mnew);
    m_i = mnew;
    float rs = 0.f;
#pragma unroll
    for (int km = 0; km < 4; ++km) {
      s16x4 pk;
#pragma unroll
      for (int rg = 0; rg < 4; ++rg) {
        float p = exp2f(sc[km][rg] - mnew);
        rs += p;
        pk[rg] = (short)f2bf(p);
      }
      *reinterpret_cast<s16x4*>(&PT[w][l16][km * 16 + quad * 4]) = pk;
    }
    rs += __shfl_xor(rs, 16, 64);
    rs += __shfl_xor(rs, 32, 64);
    l_i = l_i * alpha + rs;
#pragma unroll
    for (int dm = 0; dm < 4; ++dm)
#pragma unroll
      for (int rg = 0; rg < 4; ++rg) ot[dm][rg] *= alpha;

    // wave-private LDS round-trip: compiler orders ds_write -> ds_read via lgkmcnt
    bf16x8 p0 = *reinterpret_cast<const bf16x8*>(&PT[w][l16][quad * 8]);
    bf16x8 p1 = *reinterpret_cast<const bf16x8*>(&PT[w][l16][32 + quad * 8]);
#pragma unroll
    for (int dm = 0; dm < 4; ++dm) {
      const unsigned short* Vp = Vh + (size_t)(dm * 16 + l16) * S_LEN + kbase;
      bf16x8 av0 = *reinterpret_cast<const bf16x8*>(Vp + quad * 8);
      bf16x8 av1 = *reinterpret_cast<const bf16x8*>(Vp + 32 + quad * 8);
      ot[dm] = __builtin_amdgcn_mfma_f32_16x16x32_bf16(av0, p0, ot[dm], 0, 0, 0);
      ot[dm] = __builtin_amdgcn_mfma_f32_16x16x32_bf16(av1, p1, ot[dm], 0, 0, 0);
    }
  }

  float inv_l = 1.0f / l_i;
#pragma unroll
  for (int dm = 0; dm < 4; ++dm) {
    s16x4 pv;
#pragma unroll
    for (int rg = 0; rg < 4; ++rg) pv[rg] = (short)f2bf(ot[dm][rg] * inv_l);
    *reinterpret_cast<s16x4*>(ctx + ((size_t)(b * S_LEN) + q0 + l16) * DM + h * HD + dm * 16 + quad * 4) = pv;
  }
}

// ---------------- launch ----------------
extern "C" void kernel_launch(void* const* d_in, const int* in_sizes, int n_in,
                              void* d_out, int out_size, void* d_ws, size_t ws_size,
                              hipStream_t stream) {
  const float* x = (const float*)d_in[0];
  const float* Wq = (const float*)d_in[1];
  const float* Wkv = (const float*)d_in[2];
  const float* Wo = (const float*)d_in[3];
  const float* q_scale = (const float*)d_in[4];
  const float* k_scale = (const float*)d_in[5];
  float* out = (float*)d_out;

  char* ws = (char*)d_ws;
  size_t off = 0;
  auto alloc = [&](size_t bytes) {
    void* p = ws + off;
    off += (bytes + 255) & ~(size_t)255;
    return p;
  };
  unsigned short* xb = (unsigned short*)alloc((size_t)MROWS * DM * 2);
  unsigned short* wt1 = (unsigned short*)alloc((size_t)NQKV * DM * 2);   // [Wq^T ; Wkv^T]
  unsigned short* wot = (unsigned short*)alloc((size_t)DM * DM * 2);
  float* qkv = (float*)alloc((size_t)MROWS * NQKV * 4);
  unsigned short* qb = (unsigned short*)alloc((size_t)BATCH * NH * S_LEN * HD * 2);
  unsigned short* kbuf = (unsigned short*)alloc((size_t)BATCH * NKV * S_LEN * HD * 2);
  unsigned short* vt = (unsigned short*)alloc((size_t)BATCH * NKV * HD * S_LEN * 2);
  unsigned short* ctx = (unsigned short*)alloc((size_t)MROWS * DM * 2);

  cvt_x_kernel<<<(MROWS * DM) / 1024, 256, 0, stream>>>(x, xb, MROWS * DM);
  transpose_cvt_kernel<<<dim3(16, 16), 256, 0, stream>>>(Wq, wt1, 1024, 1024);
  transpose_cvt_kernel<<<dim3(8, 16), 256, 0, stream>>>(Wkv, wt1 + 1024 * 1024, 1024, 512);
  transpose_cvt_kernel<<<dim3(16, 16), 256, 0, stream>>>(Wo, wot, 1024, 1024);

  gemm_bt_kernel<<<dim3(NQKV / 128, MROWS / 128), 256, 0, stream>>>(xb, wt1, qkv, MROWS, NQKV, DM);

  norm_rope_kernel<<<(MROWS * 20) / 4, 256, 0, stream>>>(qkv, q_scale, k_scale, qb, kbuf);
  v_transpose_kernel<<<256, 256, 0, stream>>>(qkv, vt);

  attn_kernel<<<BATCH * NH * (S_LEN / 64), 256, 0, stream>>>(qb, kbuf, vt, ctx);

  gemm_bt_kernel<<<dim3(DM / 128, MROWS / 128), 256, 0, stream>>>(ctx, wot, out, MROWS, DM, DM);
}

// Round 3
// 283.677 us; speedup vs baseline: 1.3897x; 1.0496x over previous
//
#include <hip/hip_runtime.h>

#define S_LEN 2048
#define BATCH 2
#define DM    1024
#define NH    16
#define NKV   4
#define HD    64
#define MROWS (BATCH * S_LEN)   // 4096
#define NQKV  1536              // 1024 q + 512 kv

typedef __attribute__((ext_vector_type(8))) short bf16x8;
typedef __attribute__((ext_vector_type(4))) short s16x4;
typedef __attribute__((ext_vector_type(4))) float f32x4;

__device__ __forceinline__ unsigned short f2bf(float f) {
  unsigned int u = __float_as_uint(f);
  u += 0x7FFF + ((u >> 16) & 1);   // RNE
  return (unsigned short)(u >> 16);
}

// ---------------- x -> bf16 ----------------
__global__ __launch_bounds__(256) void cvt_x_kernel(const float* __restrict__ x,
                                                    unsigned short* __restrict__ xb, int n) {
  int i = (blockIdx.x * 256 + threadIdx.x) * 4;
  if (i < n) {
    float4 v = *reinterpret_cast<const float4*>(x + i);
    xb[i + 0] = f2bf(v.x);
    xb[i + 1] = f2bf(v.y);
    xb[i + 2] = f2bf(v.z);
    xb[i + 3] = f2bf(v.w);
  }
}

// ---------------- W (RxC fp32) -> W^T (CxR bf16) ----------------
__global__ __launch_bounds__(256) void transpose_cvt_kernel(const float* __restrict__ in,
                                                            unsigned short* __restrict__ out,
                                                            int R, int C) {
  __shared__ float tile[64][65];
  int r0 = blockIdx.y * 64, c0 = blockIdx.x * 64;
  int t = threadIdx.x;
  int rl = t >> 2, cs = (t & 3) * 16;
#pragma unroll
  for (int k = 0; k < 4; ++k) {
    float4 v = *reinterpret_cast<const float4*>(in + (size_t)(r0 + rl) * C + c0 + cs + 4 * k);
    tile[rl][cs + 4 * k + 0] = v.x;
    tile[rl][cs + 4 * k + 1] = v.y;
    tile[rl][cs + 4 * k + 2] = v.z;
    tile[rl][cs + 4 * k + 3] = v.w;
  }
  __syncthreads();
  int cl = t >> 2, rs = (t & 3) * 16;
  bf16x8 v0, v1;
#pragma unroll
  for (int i = 0; i < 8; ++i) v0[i] = (short)f2bf(tile[rs + i][cl]);
#pragma unroll
  for (int i = 0; i < 8; ++i) v1[i] = (short)f2bf(tile[rs + 8 + i][cl]);
  unsigned short* dst = out + (size_t)(c0 + cl) * R + r0 + rs;
  *reinterpret_cast<bf16x8*>(dst) = v0;
  *reinterpret_cast<bf16x8*>(dst + 8) = v1;
}

// ------- bf16 GEMM, split-K(2) along blockIdx.z (128x128 tile, 4 waves) -------
// Cp = two concatenated MxN fp32 partial buffers; part z covers K [z*Kpart, (z+1)*Kpart)
__global__ __launch_bounds__(256) void gemm_bt_splitk(const unsigned short* __restrict__ A,
                                                      const unsigned short* __restrict__ BT,
                                                      float* __restrict__ Cp,
                                                      int M, int N, int Kpart, int Ktot) {
  __shared__ __align__(16) unsigned short As[128][72];
  __shared__ __align__(16) unsigned short Bs[128][72];
  int z = blockIdx.z;
  float* C = Cp + (size_t)z * M * N;
  int kbeg = z * Kpart;
  int row0 = blockIdx.y * 128, col0 = blockIdx.x * 128;
  int t = threadIdx.x;
  int w = t >> 6, lane = t & 63, quad = lane >> 4, l16 = lane & 15;
  int wm = w & 1, wn = w >> 1;
  int sr = t >> 2, scc = (t & 3) * 16;

  f32x4 acc[4][4];
#pragma unroll
  for (int i = 0; i < 4; ++i)
#pragma unroll
    for (int j = 0; j < 4; ++j) acc[i][j] = (f32x4){0.f, 0.f, 0.f, 0.f};

  for (int k0 = kbeg; k0 < kbeg + Kpart; k0 += 64) {
    const bf16x8* ga0 = reinterpret_cast<const bf16x8*>(A + (size_t)(row0 + sr) * Ktot + k0 + scc);
    const bf16x8* ga1 = reinterpret_cast<const bf16x8*>(A + (size_t)(row0 + 64 + sr) * Ktot + k0 + scc);
    const bf16x8* gb0 = reinterpret_cast<const bf16x8*>(BT + (size_t)(col0 + sr) * Ktot + k0 + scc);
    const bf16x8* gb1 = reinterpret_cast<const bf16x8*>(BT + (size_t)(col0 + 64 + sr) * Ktot + k0 + scc);
    bf16x8 a00 = ga0[0], a01 = ga0[1], a10 = ga1[0], a11 = ga1[1];
    bf16x8 b00 = gb0[0], b01 = gb0[1], b10 = gb1[0], b11 = gb1[1];
    *reinterpret_cast<bf16x8*>(&As[sr][scc]) = a00;
    *reinterpret_cast<bf16x8*>(&As[sr][scc + 8]) = a01;
    *reinterpret_cast<bf16x8*>(&As[64 + sr][scc]) = a10;
    *reinterpret_cast<bf16x8*>(&As[64 + sr][scc + 8]) = a11;
    *reinterpret_cast<bf16x8*>(&Bs[sr][scc]) = b00;
    *reinterpret_cast<bf16x8*>(&Bs[sr][scc + 8]) = b01;
    *reinterpret_cast<bf16x8*>(&Bs[64 + sr][scc]) = b10;
    *reinterpret_cast<bf16x8*>(&Bs[64 + sr][scc + 8]) = b11;
    __syncthreads();
#pragma unroll
    for (int ks = 0; ks < 2; ++ks) {
      bf16x8 af[4], bfr[4];
#pragma unroll
      for (int i = 0; i < 4; ++i)
        af[i] = *reinterpret_cast<const bf16x8*>(&As[wm * 64 + i * 16 + l16][ks * 32 + quad * 8]);
#pragma unroll
      for (int i = 0; i < 4; ++i)
        bfr[i] = *reinterpret_cast<const bf16x8*>(&Bs[wn * 64 + i * 16 + l16][ks * 32 + quad * 8]);
#pragma unroll
      for (int am = 0; am < 4; ++am)
#pragma unroll
        for (int bn = 0; bn < 4; ++bn)
          acc[am][bn] = __builtin_amdgcn_mfma_f32_16x16x32_bf16(af[am], bfr[bn], acc[am][bn], 0, 0, 0);
    }
    __syncthreads();
  }
#pragma unroll
  for (int am = 0; am < 4; ++am)
#pragma unroll
    for (int bn = 0; bn < 4; ++bn) {
      int row = row0 + wm * 64 + am * 16 + quad * 4;
      float* Cptr = C + (size_t)row * N + col0 + wn * 64 + bn * 16 + l16;
#pragma unroll
      for (int rg = 0; rg < 4; ++rg) Cptr[(size_t)rg * N] = acc[am][bn][rg];
    }
}

// ---------------- RMSNorm + RoPE (reads the two split-K partials) ----------------
// k pre-scaled by 0.125*log2(e) so attention softmax runs in exp2 domain
__global__ __launch_bounds__(256) void norm_rope_kernel(const float* __restrict__ qkv,
                                                        const float* __restrict__ q_scale,
                                                        const float* __restrict__ k_scale,
                                                        unsigned short* __restrict__ qb,
                                                        unsigned short* __restrict__ kbuf) {
  const size_t HALFQ = (size_t)MROWS * NQKV;
  int wid = (blockIdx.x * 256 + threadIdx.x) >> 6;
  int lane = threadIdx.x & 63;
  int r = wid / 20, hh = wid % 20;         // r = b*S + s
  int b = r >> 11, s = r & 2047;
  size_t sidx;
  const float* scale;
  unsigned short* dst;
  float post;
  if (hh < 16) {
    sidx = (size_t)r * NQKV + hh * 64;
    scale = q_scale;
    dst = qb + ((size_t)(b * NH + hh) * S_LEN + s) * HD;
    post = 1.0f;
  } else {
    int kvh = hh - 16;
    sidx = (size_t)r * NQKV + 1024 + kvh * 64;
    scale = k_scale;
    dst = kbuf + ((size_t)(b * NKV + kvh) * S_LEN + s) * HD;
    post = 0.125f * 1.44269504088896f;   // fold score scale + log2(e) into k
  }
  float v = qkv[sidx + lane] + qkv[sidx + HALFQ + lane];
  float ss = v * v;
#pragma unroll
  for (int m = 1; m < 64; m <<= 1) ss += __shfl_xor(ss, m, 64);
  float rms = sqrtf(ss * (1.0f / 64.0f) + 1e-5f);
  float nv = v / rms * scale[lane];
  int dh = lane & 31;
  float inv = exp2f((float)dh * (-13.2877123795495f / 32.0f));  // 10000^(-dh/32)
  float f = (float)s * inv;
  float c = cosf(f), sn = sinf(f);
  float partner = __shfl_xor(nv, 32, 64);
  float outv = (lane < 32) ? (nv * c - partner * sn) : (partner * sn + nv * c);
  dst[lane] = f2bf(outv * post);
}

// ------- V: (s,d) fp32 slice of qkv partials -> vT (B,NKV,64,S) bf16 -------
__global__ __launch_bounds__(256) void v_transpose_kernel(const float* __restrict__ qkv,
                                                          unsigned short* __restrict__ vt) {
  const size_t HALFQ = (size_t)MROWS * NQKV;
  __shared__ float tile[64][65];
  int bkv = blockIdx.x >> 5;              // 0..7 = b*NKV+kvh
  int b = bkv >> 2, kvh = bkv & 3;
  int s0 = (blockIdx.x & 31) * 64;
  int t = threadIdx.x;
  int sl = t >> 2, ds = (t & 3) * 16;
  const float* src = qkv + (size_t)(b * S_LEN + s0 + sl) * NQKV + 1280 + kvh * 64 + ds;
#pragma unroll
  for (int k = 0; k < 4; ++k) {
    float4 v = *reinterpret_cast<const float4*>(src + 4 * k);
    float4 v2 = *reinterpret_cast<const float4*>(src + HALFQ + 4 * k);
    tile[sl][ds + 4 * k + 0] = v.x + v2.x;
    tile[sl][ds + 4 * k + 1] = v.y + v2.y;
    tile[sl][ds + 4 * k + 2] = v.z + v2.z;
    tile[sl][ds + 4 * k + 3] = v.w + v2.w;
  }
  __syncthreads();
  int d = t >> 2, ssg = (t & 3) * 16;
  bf16x8 v0, v1;
#pragma unroll
  for (int i = 0; i < 8; ++i) v0[i] = (short)f2bf(tile[ssg + i][d]);
#pragma unroll
  for (int i = 0; i < 8; ++i) v1[i] = (short)f2bf(tile[ssg + 8 + i][d]);
  unsigned short* dst = vt + ((size_t)bkv * 64 + d) * S_LEN + s0 + ssg;
  *reinterpret_cast<bf16x8*>(dst) = v0;
  *reinterpret_cast<bf16x8*>(dst + 8) = v1;
}

// ---------------- causal flash attention, fixed-max softmax ----------------
// scores in log2 domain (k pre-scaled); |s| <= 11.6 so p = exp2(s - 16) is exact-safe.
// One wave per block, 16 q-rows per wave. S^T = K.Q^T (q on lane&15), O^T = V^T.P^T.
// No barriers, no shuffles in the loop, no online rescale.
__global__ __launch_bounds__(64) void attn_kernel(const unsigned short* __restrict__ qb,
                                                  const unsigned short* __restrict__ kbuf,
                                                  const unsigned short* __restrict__ vt,
                                                  unsigned short* __restrict__ ctx) {
  __shared__ __align__(16) unsigned short PT[16][72];
  int bh = blockIdx.x & 31;
  int t16 = 127 - (int)(blockIdx.x >> 5);   // heavy tiles first
  int b = bh >> 4, h = bh & 15, kvh = h >> 2;
  int lane = threadIdx.x;
  int quad = lane >> 4, l16 = lane & 15;
  int qr = t16 * 16 + l16;
  const unsigned short* Q = qb + (size_t)(b * NH + h) * S_LEN * HD;
  const unsigned short* Kh = kbuf + (size_t)(b * NKV + kvh) * S_LEN * HD;
  const unsigned short* Vh = vt + (size_t)(b * NKV + kvh) * HD * S_LEN;

  bf16x8 bq0 = *reinterpret_cast<const bf16x8*>(Q + (size_t)qr * HD + quad * 8);
  bf16x8 bq1 = *reinterpret_cast<const bf16x8*>(Q + (size_t)qr * HD + 32 + quad * 8);

  f32x4 ot[4];
#pragma unroll
  for (int i = 0; i < 4; ++i) ot[i] = (f32x4){0.f, 0.f, 0.f, 0.f};
  f32x4 rs4 = {0.f, 0.f, 0.f, 0.f};

  int nkb = (t16 >> 2) + 1;

  // current K tile in regs (prefetched each iteration)
  bf16x8 kc0[4], kc1[4];
#pragma unroll
  for (int km = 0; km < 4; ++km) {
    const unsigned short* kp = Kh + (size_t)(km * 16 + l16) * HD;
    kc0[km] = *reinterpret_cast<const bf16x8*>(kp + quad * 8);
    kc1[km] = *reinterpret_cast<const bf16x8*>(kp + 32 + quad * 8);
  }

  for (int kbi = 0; kbi < nkb; ++kbi) {
    bool last = (kbi == nkb - 1);
    int kbase = kbi << 6;
    // QK^T (transposed scores: key = quad*4+rg, q = l16)
    f32x4 sc[4];
#pragma unroll
    for (int km = 0; km < 4; ++km) {
      f32x4 s = {0.f, 0.f, 0.f, 0.f};
      s = __builtin_amdgcn_mfma_f32_16x16x32_bf16(kc0[km], bq0, s, 0, 0, 0);
      s = __builtin_amdgcn_mfma_f32_16x16x32_bf16(kc1[km], bq1, s, 0, 0, 0);
      sc[km] = s;
    }
    // V loads for this tile (consumed after softmax; latency hidden by exp phase)
    bf16x8 va0[4], va1[4];
#pragma unroll
    for (int dm = 0; dm < 4; ++dm) {
      const unsigned short* vp = Vh + (size_t)(dm * 16 + l16) * S_LEN + kbase;
      va0[dm] = *reinterpret_cast<const bf16x8*>(vp + quad * 8);
      va1[dm] = *reinterpret_cast<const bf16x8*>(vp + 32 + quad * 8);
    }
    if (!last) {
      // prefetch next K tile (current regs already consumed by the MFMAs above)
      const unsigned short* kp = Kh + (size_t)(kbase + 64 + l16) * HD;
#pragma unroll
      for (int km = 0; km < 4; ++km) {
        kc0[km] = *reinterpret_cast<const bf16x8*>(kp + (size_t)(km * 16) * HD + quad * 8);
        kc1[km] = *reinterpret_cast<const bf16x8*>(kp + (size_t)(km * 16) * HD + 32 + quad * 8);
      }
    } else {
      // causal mask: only the diagonal (final) tile needs it
#pragma unroll
      for (int km = 0; km < 4; ++km)
#pragma unroll
        for (int rg = 0; rg < 4; ++rg)
          if (kbase + km * 16 + quad * 4 + rg > qr) sc[km][rg] = -1e30f;
    }
    // p = exp2(s - 16): fixed max (scores bounded by 11.6), truncation-pack to bf16
#pragma unroll
    for (int km = 0; km < 4; ++km) {
      f32x4 p;
#pragma unroll
      for (int rg = 0; rg < 4; ++rg) p[rg] = exp2f(sc[km][rg] - 16.0f);
      rs4 += p;
      uint2 pw;
      pw.x = (__float_as_uint(p[1]) & 0xffff0000u) | (__float_as_uint(p[0]) >> 16);
      pw.y = (__float_as_uint(p[3]) & 0xffff0000u) | (__float_as_uint(p[2]) >> 16);
      *reinterpret_cast<uint2*>(&PT[l16][km * 16 + quad * 4]) = pw;
    }
    // wave-private LDS roundtrip: C-layout -> B-operand layout
    bf16x8 p0 = *reinterpret_cast<const bf16x8*>(&PT[l16][quad * 8]);
    bf16x8 p1 = *reinterpret_cast<const bf16x8*>(&PT[l16][32 + quad * 8]);
#pragma unroll
    for (int dm = 0; dm < 4; ++dm) {
      ot[dm] = __builtin_amdgcn_mfma_f32_16x16x32_bf16(va0[dm], p0, ot[dm], 0, 0, 0);
      ot[dm] = __builtin_amdgcn_mfma_f32_16x16x32_bf16(va1[dm], p1, ot[dm], 0, 0, 0);
    }
  }

  float l = (rs4[0] + rs4[1]) + (rs4[2] + rs4[3]);
  l += __shfl_xor(l, 16, 64);
  l += __shfl_xor(l, 32, 64);
  float inv_l = 1.0f / l;
#pragma unroll
  for (int dm = 0; dm < 4; ++dm) {
    s16x4 pv;
#pragma unroll
    for (int rg = 0; rg < 4; ++rg) pv[rg] = (short)f2bf(ot[dm][rg] * inv_l);
    *reinterpret_cast<s16x4*>(ctx + ((size_t)(b * S_LEN) + qr) * DM + h * HD + dm * 16 + quad * 4) = pv;
  }
}

// ---------------- out = partial0 + partial1 ----------------
__global__ __launch_bounds__(256) void add_out_kernel(const float* __restrict__ a,
                                                      const float* __restrict__ b,
                                                      float* __restrict__ o, int n) {
  int i = (blockIdx.x * 256 + threadIdx.x) * 4;
  if (i < n) {
    float4 x = *reinterpret_cast<const float4*>(a + i);
    float4 y = *reinterpret_cast<const float4*>(b + i);
    float4 r = {x.x + y.x, x.y + y.y, x.z + y.z, x.w + y.w};
    *reinterpret_cast<float4*>(o + i) = r;
  }
}

// ---------------- launch ----------------
extern "C" void kernel_launch(void* const* d_in, const int* in_sizes, int n_in,
                              void* d_out, int out_size, void* d_ws, size_t ws_size,
                              hipStream_t stream) {
  const float* x = (const float*)d_in[0];
  const float* Wq = (const float*)d_in[1];
  const float* Wkv = (const float*)d_in[2];
  const float* Wo = (const float*)d_in[3];
  const float* q_scale = (const float*)d_in[4];
  const float* k_scale = (const float*)d_in[5];
  float* out = (float*)d_out;

  char* ws = (char*)d_ws;
  size_t off = 0;
  auto alloc = [&](size_t bytes) {
    void* p = ws + off;
    off += (bytes + 255) & ~(size_t)255;
    return p;
  };
  unsigned short* xb = (unsigned short*)alloc((size_t)MROWS * DM * 2);
  unsigned short* wt1 = (unsigned short*)alloc((size_t)NQKV * DM * 2);   // [Wq^T ; Wkv^T]
  unsigned short* wot = (unsigned short*)alloc((size_t)DM * DM * 2);
  float* qkvp = (float*)alloc(2 * (size_t)MROWS * NQKV * 4);             // split-K partials
  unsigned short* qb = (unsigned short*)alloc((size_t)BATCH * NH * S_LEN * HD * 2);
  unsigned short* kbuf = (unsigned short*)alloc((size_t)BATCH * NKV * S_LEN * HD * 2);
  unsigned short* vt = (unsigned short*)alloc((size_t)BATCH * NKV * HD * S_LEN * 2);
  unsigned short* ctx = (unsigned short*)alloc((size_t)MROWS * DM * 2);
  float* outp = (float*)alloc(2 * (size_t)MROWS * DM * 4);               // split-K partials

  cvt_x_kernel<<<(MROWS * DM) / 1024, 256, 0, stream>>>(x, xb, MROWS * DM);
  transpose_cvt_kernel<<<dim3(16, 16), 256, 0, stream>>>(Wq, wt1, 1024, 1024);
  transpose_cvt_kernel<<<dim3(8, 16), 256, 0, stream>>>(Wkv, wt1 + 1024 * 1024, 1024, 512);
  transpose_cvt_kernel<<<dim3(16, 16), 256, 0, stream>>>(Wo, wot, 1024, 1024);

  gemm_bt_splitk<<<dim3(NQKV / 128, MROWS / 128, 2), 256, 0, stream>>>(xb, wt1, qkvp,
                                                                       MROWS, NQKV, 512, DM);

  norm_rope_kernel<<<(MROWS * 20) / 4, 256, 0, stream>>>(qkvp, q_scale, k_scale, qb, kbuf);
  v_transpose_kernel<<<256, 256, 0, stream>>>(qkvp, vt);

  attn_kernel<<<BATCH * NH * (S_LEN / 16), 64, 0, stream>>>(qb, kbuf, vt, ctx);

  gemm_bt_splitk<<<dim3(DM / 128, MROWS / 128, 2), 256, 0, stream>>>(ctx, wot, outp,
                                                                     MROWS, DM, 512, DM);
  add_out_kernel<<<(MROWS * DM) / 1024, 256, 0, stream>>>(outp, outp + (size_t)MROWS * DM,
                                                          out, MROWS * DM);
}

// Round 4
// 238.891 us; speedup vs baseline: 1.6502x; 1.1875x over previous
//
#include <hip/hip_runtime.h>

#define S_LEN 2048
#define BATCH 2
#define DM    1024
#define NH    16
#define NKV   4
#define HD    64
#define MROWS (BATCH * S_LEN)   // 4096
#define NQKV  1536              // 1024 q + 512 kv

typedef __attribute__((ext_vector_type(8))) short bf16x8;
typedef __attribute__((ext_vector_type(4))) short s16x4;
typedef __attribute__((ext_vector_type(4))) float f32x4;

__device__ __forceinline__ unsigned short f2bf(float f) {
  unsigned int u = __float_as_uint(f);
  u += 0x7FFF + ((u >> 16) & 1);   // RNE
  return (unsigned short)(u >> 16);
}

__device__ __forceinline__ void gload_lds16(const unsigned short* g, unsigned short* l) {
  __builtin_amdgcn_global_load_lds((const __attribute__((address_space(1))) void*)g,
                                   (__attribute__((address_space(3))) void*)l, 16, 0, 0);
}

// ---------------- x -> bf16 ----------------
__global__ __launch_bounds__(256) void cvt_x_kernel(const float* __restrict__ x,
                                                    unsigned short* __restrict__ xb, int n) {
  int i = (blockIdx.x * 256 + threadIdx.x) * 4;
  if (i < n) {
    float4 v = *reinterpret_cast<const float4*>(x + i);
    xb[i + 0] = f2bf(v.x);
    xb[i + 1] = f2bf(v.y);
    xb[i + 2] = f2bf(v.z);
    xb[i + 3] = f2bf(v.w);
  }
}

// ---------------- W (RxC fp32) -> W^T (CxR bf16) ----------------
__global__ __launch_bounds__(256) void transpose_cvt_kernel(const float* __restrict__ in,
                                                            unsigned short* __restrict__ out,
                                                            int R, int C) {
  __shared__ float tile[64][65];
  int r0 = blockIdx.y * 64, c0 = blockIdx.x * 64;
  int t = threadIdx.x;
  int rl = t >> 2, cs = (t & 3) * 16;
#pragma unroll
  for (int k = 0; k < 4; ++k) {
    float4 v = *reinterpret_cast<const float4*>(in + (size_t)(r0 + rl) * C + c0 + cs + 4 * k);
    tile[rl][cs + 4 * k + 0] = v.x;
    tile[rl][cs + 4 * k + 1] = v.y;
    tile[rl][cs + 4 * k + 2] = v.z;
    tile[rl][cs + 4 * k + 3] = v.w;
  }
  __syncthreads();
  int cl = t >> 2, rs = (t & 3) * 16;
  bf16x8 v0, v1;
#pragma unroll
  for (int i = 0; i < 8; ++i) v0[i] = (short)f2bf(tile[rs + i][cl]);
#pragma unroll
  for (int i = 0; i < 8; ++i) v1[i] = (short)f2bf(tile[rs + 8 + i][cl]);
  unsigned short* dst = out + (size_t)(c0 + cl) * R + r0 + rs;
  *reinterpret_cast<bf16x8*>(dst) = v0;
  *reinterpret_cast<bf16x8*>(dst + 8) = v1;
}

// ------- bf16 GEMM, split-K(2), m97 structure: global_load_lds staging -------
// Cp = two concatenated MxN fp32 partial buffers; part z covers K [z*Kpart, (z+1)*Kpart)
__global__ __launch_bounds__(256) void gemm_bt_splitk(const unsigned short* __restrict__ A,
                                                      const unsigned short* __restrict__ BT,
                                                      float* __restrict__ Cp,
                                                      int M, int N, int Kpart, int Ktot) {
  __shared__ __align__(16) unsigned short As[128 * 64];
  __shared__ __align__(16) unsigned short Bs[128 * 64];
  int z = blockIdx.z;
  float* C = Cp + (size_t)z * M * N;
  int kbeg = z * Kpart;
  int row0 = blockIdx.y * 128, col0 = blockIdx.x * 128;
  int t = threadIdx.x;
  int w = t >> 6, lane = t & 63, quad = lane >> 4, l16 = lane & 15;
  int wm = w & 1, wn = w >> 1;
  int srow = lane >> 3;            // 0..7 within one 1KB instr
  int scol = (lane & 7) * 8;       // element column

  f32x4 acc[4][4];
#pragma unroll
  for (int i = 0; i < 4; ++i)
#pragma unroll
    for (int j = 0; j < 4; ++j) acc[i][j] = (f32x4){0.f, 0.f, 0.f, 0.f};

  for (int k0 = kbeg; k0 < kbeg + Kpart; k0 += 64) {
    // async global -> LDS staging, 1 KB per instr per wave (m97 pattern)
#pragma unroll
    for (int j = 0; j < 4; ++j) {
      int r = w * 32 + j * 8 + srow;
      gload_lds16(A + (size_t)(row0 + r) * Ktot + k0 + scol, &As[(w * 32 + j * 8) * 64]);
      gload_lds16(BT + (size_t)(col0 + r) * Ktot + k0 + scol, &Bs[(w * 32 + j * 8) * 64]);
    }
    __syncthreads();   // drains vmcnt -> staging complete
#pragma unroll
    for (int ks = 0; ks < 2; ++ks) {
      bf16x8 af[4], bfr[4];
#pragma unroll
      for (int i = 0; i < 4; ++i)
        af[i] = *reinterpret_cast<const bf16x8*>(&As[(wm * 64 + i * 16 + l16) * 64 + ks * 32 + quad * 8]);
#pragma unroll
      for (int i = 0; i < 4; ++i)
        bfr[i] = *reinterpret_cast<const bf16x8*>(&Bs[(wn * 64 + i * 16 + l16) * 64 + ks * 32 + quad * 8]);
#pragma unroll
      for (int am = 0; am < 4; ++am)
#pragma unroll
        for (int bn = 0; bn < 4; ++bn)
          acc[am][bn] = __builtin_amdgcn_mfma_f32_16x16x32_bf16(af[am], bfr[bn], acc[am][bn], 0, 0, 0);
    }
    __syncthreads();
  }
#pragma unroll
  for (int am = 0; am < 4; ++am)
#pragma unroll
    for (int bn = 0; bn < 4; ++bn) {
      int row = row0 + wm * 64 + am * 16 + quad * 4;
      float* Cptr = C + (size_t)row * N + col0 + wn * 64 + bn * 16 + l16;
#pragma unroll
      for (int rg = 0; rg < 4; ++rg) Cptr[(size_t)rg * N] = acc[am][bn][rg];
    }
}

// ---------------- RMSNorm + RoPE (reads the two split-K partials) ----------------
// k pre-scaled by 0.125*log2(e) so attention softmax runs in exp2 domain
__global__ __launch_bounds__(256) void norm_rope_kernel(const float* __restrict__ qkv,
                                                        const float* __restrict__ q_scale,
                                                        const float* __restrict__ k_scale,
                                                        unsigned short* __restrict__ qb,
                                                        unsigned short* __restrict__ kbuf) {
  const size_t HALFQ = (size_t)MROWS * NQKV;
  int wid = (blockIdx.x * 256 + threadIdx.x) >> 6;
  int lane = threadIdx.x & 63;
  int r = wid / 20, hh = wid % 20;         // r = b*S + s
  int b = r >> 11, s = r & 2047;
  size_t sidx;
  const float* scale;
  unsigned short* dst;
  float post;
  if (hh < 16) {
    sidx = (size_t)r * NQKV + hh * 64;
    scale = q_scale;
    dst = qb + ((size_t)(b * NH + hh) * S_LEN + s) * HD;
    post = 1.0f;
  } else {
    int kvh = hh - 16;
    sidx = (size_t)r * NQKV + 1024 + kvh * 64;
    scale = k_scale;
    dst = kbuf + ((size_t)(b * NKV + kvh) * S_LEN + s) * HD;
    post = 0.125f * 1.44269504088896f;   // fold score scale + log2(e) into k
  }
  float v = qkv[sidx + lane] + qkv[sidx + HALFQ + lane];
  float ss = v * v;
#pragma unroll
  for (int m = 1; m < 64; m <<= 1) ss += __shfl_xor(ss, m, 64);
  float rms = sqrtf(ss * (1.0f / 64.0f) + 1e-5f);
  float nv = v / rms * scale[lane];
  int dh = lane & 31;
  float inv = exp2f((float)dh * (-13.2877123795495f / 32.0f));  // 10000^(-dh/32)
  float f = (float)s * inv;
  float c = cosf(f), sn = sinf(f);
  float partner = __shfl_xor(nv, 32, 64);
  float outv = (lane < 32) ? (nv * c - partner * sn) : (partner * sn + nv * c);
  dst[lane] = f2bf(outv * post);
}

// ------- V: (s,d) fp32 slice of qkv partials -> vT (B,NKV,64,S) bf16 -------
__global__ __launch_bounds__(256) void v_transpose_kernel(const float* __restrict__ qkv,
                                                          unsigned short* __restrict__ vt) {
  const size_t HALFQ = (size_t)MROWS * NQKV;
  __shared__ float tile[64][65];
  int bkv = blockIdx.x >> 5;              // 0..7 = b*NKV+kvh
  int b = bkv >> 2, kvh = bkv & 3;
  int s0 = (blockIdx.x & 31) * 64;
  int t = threadIdx.x;
  int sl = t >> 2, ds = (t & 3) * 16;
  const float* src = qkv + (size_t)(b * S_LEN + s0 + sl) * NQKV + 1280 + kvh * 64 + ds;
#pragma unroll
  for (int k = 0; k < 4; ++k) {
    float4 v = *reinterpret_cast<const float4*>(src + 4 * k);
    float4 v2 = *reinterpret_cast<const float4*>(src + HALFQ + 4 * k);
    tile[sl][ds + 4 * k + 0] = v.x + v2.x;
    tile[sl][ds + 4 * k + 1] = v.y + v2.y;
    tile[sl][ds + 4 * k + 2] = v.z + v2.z;
    tile[sl][ds + 4 * k + 3] = v.w + v2.w;
  }
  __syncthreads();
  int d = t >> 2, ssg = (t & 3) * 16;
  bf16x8 v0, v1;
#pragma unroll
  for (int i = 0; i < 8; ++i) v0[i] = (short)f2bf(tile[ssg + i][d]);
#pragma unroll
  for (int i = 0; i < 8; ++i) v1[i] = (short)f2bf(tile[ssg + 8 + i][d]);
  unsigned short* dst = vt + ((size_t)bkv * 64 + d) * S_LEN + s0 + ssg;
  *reinterpret_cast<bf16x8*>(dst) = v0;
  *reinterpret_cast<bf16x8*>(dst + 8) = v1;
}

// ------- causal flash attention: 32 q-columns per wave, fixed-max exp2 -------
// S^T = K.Q^T (q on lane&15), O^T = V^T.P^T. l computed via ones-row MFMA.
// No barriers, no shuffles, no bias subtract (2^0 scale cancels in O/l).
__global__ __launch_bounds__(64) void attn_kernel(const unsigned short* __restrict__ qb,
                                                  const unsigned short* __restrict__ kbuf,
                                                  const unsigned short* __restrict__ vt,
                                                  unsigned short* __restrict__ ctx) {
  __shared__ __align__(16) unsigned short PT[2][16][72];
  int bh = blockIdx.x & 31;
  int t32 = 63 - (int)(blockIdx.x >> 5);   // heavy tiles first
  int b = bh >> 4, h = bh & 15, kvh = h >> 2;
  int lane = threadIdx.x;
  int quad = lane >> 4, l16 = lane & 15;
  int qa = t32 * 32 + l16;                 // q-group a; group b = qa + 16
  const unsigned short* Q = qb + (size_t)(b * NH + h) * S_LEN * HD;
  const unsigned short* Kh = kbuf + (size_t)(b * NKV + kvh) * S_LEN * HD;
  const unsigned short* Vh = vt + (size_t)(b * NKV + kvh) * HD * S_LEN;

  bf16x8 bqa0 = *reinterpret_cast<const bf16x8*>(Q + (size_t)qa * HD + quad * 8);
  bf16x8 bqa1 = *reinterpret_cast<const bf16x8*>(Q + (size_t)qa * HD + 32 + quad * 8);
  bf16x8 bqb0 = *reinterpret_cast<const bf16x8*>(Q + (size_t)(qa + 16) * HD + quad * 8);
  bf16x8 bqb1 = *reinterpret_cast<const bf16x8*>(Q + (size_t)(qa + 16) * HD + 32 + quad * 8);

  bf16x8 ones;
#pragma unroll
  for (int i = 0; i < 8; ++i) ones[i] = (short)0x3F80;   // bf16 1.0

  f32x4 ot[2][4];
#pragma unroll
  for (int g = 0; g < 2; ++g)
#pragma unroll
    for (int i = 0; i < 4; ++i) ot[g][i] = (f32x4){0.f, 0.f, 0.f, 0.f};
  f32x4 ol[2] = {(f32x4){0.f, 0.f, 0.f, 0.f}, (f32x4){0.f, 0.f, 0.f, 0.f}};

  int nkb = (t32 >> 1) + 1;

  bf16x8 kc0[4], kc1[4];
#pragma unroll
  for (int km = 0; km < 4; ++km) {
    const unsigned short* kp = Kh + (size_t)(km * 16 + l16) * HD;
    kc0[km] = *reinterpret_cast<const bf16x8*>(kp + quad * 8);
    kc1[km] = *reinterpret_cast<const bf16x8*>(kp + 32 + quad * 8);
  }

  for (int kbi = 0; kbi < nkb; ++kbi) {
    bool last = (kbi == nkb - 1);
    int kbase = kbi << 6;
    f32x4 sa[4], sb[4];
#pragma unroll
    for (int km = 0; km < 4; ++km) {
      f32x4 s = {0.f, 0.f, 0.f, 0.f};
      s = __builtin_amdgcn_mfma_f32_16x16x32_bf16(kc0[km], bqa0, s, 0, 0, 0);
      s = __builtin_amdgcn_mfma_f32_16x16x32_bf16(kc1[km], bqa1, s, 0, 0, 0);
      sa[km] = s;
      f32x4 s2 = {0.f, 0.f, 0.f, 0.f};
      s2 = __builtin_amdgcn_mfma_f32_16x16x32_bf16(kc0[km], bqb0, s2, 0, 0, 0);
      s2 = __builtin_amdgcn_mfma_f32_16x16x32_bf16(kc1[km], bqb1, s2, 0, 0, 0);
      sb[km] = s2;
    }
    // V loads for this tile (latency hidden by exp/pack phase)
    bf16x8 va0[4], va1[4];
#pragma unroll
    for (int dm = 0; dm < 4; ++dm) {
      const unsigned short* vp = Vh + (size_t)(dm * 16 + l16) * S_LEN + kbase;
      va0[dm] = *reinterpret_cast<const bf16x8*>(vp + quad * 8);
      va1[dm] = *reinterpret_cast<const bf16x8*>(vp + 32 + quad * 8);
    }
    if (!last) {
      const unsigned short* kp = Kh + (size_t)(kbase + 64 + l16) * HD;
#pragma unroll
      for (int km = 0; km < 4; ++km) {
        kc0[km] = *reinterpret_cast<const bf16x8*>(kp + (size_t)(km * 16) * HD + quad * 8);
        kc1[km] = *reinterpret_cast<const bf16x8*>(kp + (size_t)(km * 16) * HD + 32 + quad * 8);
      }
    } else {
      // causal mask on the diagonal tile(s) only
#pragma unroll
      for (int km = 0; km < 4; ++km)
#pragma unroll
        for (int rg = 0; rg < 4; ++rg) {
          int key = kbase + km * 16 + quad * 4 + rg;
          if (key > qa) sa[km][rg] = -1e30f;
          if (key > qa + 16) sb[km][rg] = -1e30f;
        }
    }
    // p = exp2(s); one v_perm per pair packs truncated bf16
#pragma unroll
    for (int km = 0; km < 4; ++km) {
      float a0 = exp2f(sa[km][0]), a1 = exp2f(sa[km][1]);
      float a2 = exp2f(sa[km][2]), a3 = exp2f(sa[km][3]);
      uint2 pw;
      pw.x = __builtin_amdgcn_perm(__float_as_uint(a1), __float_as_uint(a0), 0x07060302);
      pw.y = __builtin_amdgcn_perm(__float_as_uint(a3), __float_as_uint(a2), 0x07060302);
      *reinterpret_cast<uint2*>(&PT[0][l16][km * 16 + quad * 4]) = pw;
      float b0 = exp2f(sb[km][0]), b1 = exp2f(sb[km][1]);
      float b2 = exp2f(sb[km][2]), b3 = exp2f(sb[km][3]);
      uint2 qw;
      qw.x = __builtin_amdgcn_perm(__float_as_uint(b1), __float_as_uint(b0), 0x07060302);
      qw.y = __builtin_amdgcn_perm(__float_as_uint(b3), __float_as_uint(b2), 0x07060302);
      *reinterpret_cast<uint2*>(&PT[1][l16][km * 16 + quad * 4]) = qw;
    }
    // wave-private LDS roundtrip: C-layout -> B-operand layout
    bf16x8 pa0 = *reinterpret_cast<const bf16x8*>(&PT[0][l16][quad * 8]);
    bf16x8 pa1 = *reinterpret_cast<const bf16x8*>(&PT[0][l16][32 + quad * 8]);
    bf16x8 pb0 = *reinterpret_cast<const bf16x8*>(&PT[1][l16][quad * 8]);
    bf16x8 pb1 = *reinterpret_cast<const bf16x8*>(&PT[1][l16][32 + quad * 8]);
    // l via ones-row MFMA (replaces per-score adds + epilogue shuffles)
    ol[0] = __builtin_amdgcn_mfma_f32_16x16x32_bf16(ones, pa0, ol[0], 0, 0, 0);
    ol[0] = __builtin_amdgcn_mfma_f32_16x16x32_bf16(ones, pa1, ol[0], 0, 0, 0);
    ol[1] = __builtin_amdgcn_mfma_f32_16x16x32_bf16(ones, pb0, ol[1], 0, 0, 0);
    ol[1] = __builtin_amdgcn_mfma_f32_16x16x32_bf16(ones, pb1, ol[1], 0, 0, 0);
#pragma unroll
    for (int dm = 0; dm < 4; ++dm) {
      ot[0][dm] = __builtin_amdgcn_mfma_f32_16x16x32_bf16(va0[dm], pa0, ot[0][dm], 0, 0, 0);
      ot[0][dm] = __builtin_amdgcn_mfma_f32_16x16x32_bf16(va1[dm], pa1, ot[0][dm], 0, 0, 0);
      ot[1][dm] = __builtin_amdgcn_mfma_f32_16x16x32_bf16(va0[dm], pb0, ot[1][dm], 0, 0, 0);
      ot[1][dm] = __builtin_amdgcn_mfma_f32_16x16x32_bf16(va1[dm], pb1, ot[1][dm], 0, 0, 0);
    }
  }

#pragma unroll
  for (int g = 0; g < 2; ++g) {
    float inv_l = 1.0f / ol[g][0];
    size_t base = ((size_t)(b * S_LEN) + qa + g * 16) * DM + h * HD;
#pragma unroll
    for (int dm = 0; dm < 4; ++dm) {
      s16x4 pv;
#pragma unroll
      for (int rg = 0; rg < 4; ++rg) pv[rg] = (short)f2bf(ot[g][dm][rg] * inv_l);
      *reinterpret_cast<s16x4*>(ctx + base + dm * 16 + quad * 4) = pv;
    }
  }
}

// ---------------- out = partial0 + partial1 ----------------
__global__ __launch_bounds__(256) void add_out_kernel(const float* __restrict__ a,
                                                      const float* __restrict__ b,
                                                      float* __restrict__ o, int n) {
  int i = (blockIdx.x * 256 + threadIdx.x) * 4;
  if (i < n) {
    float4 x = *reinterpret_cast<const float4*>(a + i);
    float4 y = *reinterpret_cast<const float4*>(b + i);
    float4 r = {x.x + y.x, x.y + y.y, x.z + y.z, x.w + y.w};
    *reinterpret_cast<float4*>(o + i) = r;
  }
}

// ---------------- launch ----------------
extern "C" void kernel_launch(void* const* d_in, const int* in_sizes, int n_in,
                              void* d_out, int out_size, void* d_ws, size_t ws_size,
                              hipStream_t stream) {
  const float* x = (const float*)d_in[0];
  const float* Wq = (const float*)d_in[1];
  const float* Wkv = (const float*)d_in[2];
  const float* Wo = (const float*)d_in[3];
  const float* q_scale = (const float*)d_in[4];
  const float* k_scale = (const float*)d_in[5];
  float* out = (float*)d_out;

  char* ws = (char*)d_ws;
  size_t off = 0;
  auto alloc = [&](size_t bytes) {
    void* p = ws + off;
    off += (bytes + 255) & ~(size_t)255;
    return p;
  };
  unsigned short* xb = (unsigned short*)alloc((size_t)MROWS * DM * 2);
  unsigned short* wt1 = (unsigned short*)alloc((size_t)NQKV * DM * 2);   // [Wq^T ; Wkv^T]
  unsigned short* wot = (unsigned short*)alloc((size_t)DM * DM * 2);
  float* qkvp = (float*)alloc(2 * (size_t)MROWS * NQKV * 4);             // split-K partials
  unsigned short* qb = (unsigned short*)alloc((size_t)BATCH * NH * S_LEN * HD * 2);
  unsigned short* kbuf = (unsigned short*)alloc((size_t)BATCH * NKV * S_LEN * HD * 2);
  unsigned short* vt = (unsigned short*)alloc((size_t)BATCH * NKV * HD * S_LEN * 2);
  unsigned short* ctx = (unsigned short*)alloc((size_t)MROWS * DM * 2);
  float* outp = (float*)alloc(2 * (size_t)MROWS * DM * 4);               // split-K partials

  cvt_x_kernel<<<(MROWS * DM) / 1024, 256, 0, stream>>>(x, xb, MROWS * DM);
  transpose_cvt_kernel<<<dim3(16, 16), 256, 0, stream>>>(Wq, wt1, 1024, 1024);
  transpose_cvt_kernel<<<dim3(8, 16), 256, 0, stream>>>(Wkv, wt1 + 1024 * 1024, 1024, 512);
  transpose_cvt_kernel<<<dim3(16, 16), 256, 0, stream>>>(Wo, wot, 1024, 1024);

  gemm_bt_splitk<<<dim3(NQKV / 128, MROWS / 128, 2), 256, 0, stream>>>(xb, wt1, qkvp,
                                                                       MROWS, NQKV, 512, DM);

  norm_rope_kernel<<<(MROWS * 20) / 4, 256, 0, stream>>>(qkvp, q_scale, k_scale, qb, kbuf);
  v_transpose_kernel<<<256, 256, 0, stream>>>(qkvp, vt);

  attn_kernel<<<BATCH * NH * (S_LEN / 32), 64, 0, stream>>>(qb, kbuf, vt, ctx);

  gemm_bt_splitk<<<dim3(DM / 128, MROWS / 128, 2), 256, 0, stream>>>(ctx, wot, outp,
                                                                     MROWS, DM, 512, DM);
  add_out_kernel<<<(MROWS * DM) / 1024, 256, 0, stream>>>(outp, outp + (size_t)MROWS * DM,
                                                          out, MROWS * DM);
}